// Round 13
// baseline (441.760 us; speedup 1.0000x reference)
//
#include <hip/hip_runtime.h>

typedef short short8 __attribute__((ext_vector_type(8)));
typedef float f32x4 __attribute__((ext_vector_type(4)));
typedef unsigned short u16;

#define TOK_N 8192      // B*S
#define DMODEL 1024
#define NEXP 16
#define FEXP 512
#define NROUTED 14
#define KSEL 6
#define MAXT 208        // sum ceil(cnt_e/256) <= 49152/256 + 16

__device__ __forceinline__ u16 f2bf(float f) {
  unsigned u = __float_as_uint(f);
  u += 0x7fff + ((u >> 16) & 1);   // round-to-nearest-even
  return (u16)(u >> 16);
}

typedef const __attribute__((address_space(1))) unsigned int* gas_p;
typedef __attribute__((address_space(3))) unsigned int* las_p;
// wave-uniform LDS base + lane*16; per-lane global src (16B each)
__device__ __forceinline__ void gload_lds16(const void* g, void* l) {
  __builtin_amdgcn_global_load_lds((gas_p)g, (las_p)l, 16, 0, 0);
}

// ---------------- cast f32 -> bf16 (token stream) ----------------
__global__ void cast_bf16_k(const float* __restrict__ in, u16* __restrict__ out, int n8) {
  int i = blockIdx.x * blockDim.x + threadIdx.x;
  if (i >= n8) return;
  const float4* p = (const float4*)(in + (size_t)i * 8);
  float4 a = p[0], b = p[1];
  short8 v;
  v[0] = (short)f2bf(a.x); v[1] = (short)f2bf(a.y); v[2] = (short)f2bf(a.z); v[3] = (short)f2bf(a.w);
  v[4] = (short)f2bf(b.x); v[5] = (short)f2bf(b.y); v[6] = (short)f2bf(b.z); v[7] = (short)f2bf(b.w);
  *(short8*)(out + (size_t)i * 8) = v;
}

// ------------- transpose + cast: in [e][R][C] f32 -> out [e][C][R] bf16 -------------
__global__ void transpose_cast_k(const float* __restrict__ in, u16* __restrict__ out, int R, int C) {
  __shared__ u16 tile[32][33];
  int e = blockIdx.z;
  int c0 = blockIdx.x * 32, r0 = blockIdx.y * 32;
  int x = threadIdx.x, y = threadIdx.y;   // block (32,8)
  const float* ip = in + ((size_t)e * R + r0) * C + c0;
  #pragma unroll
  for (int i = 0; i < 4; i++)
    tile[y + 8 * i][x] = f2bf(ip[(size_t)(y + 8 * i) * C + x]);
  __syncthreads();
  u16* op = out + ((size_t)e * C + c0) * R + r0;
  #pragma unroll
  for (int i = 0; i < 4; i++)
    op[(size_t)(y + 8 * i) * R + x] = tile[x][y + 8 * i];
}

// ---------------- routing pass A: logits, sigmoid, stable top-4 (NO global atomics) ----
__global__ void routing_k(const float* __restrict__ selin, const float* __restrict__ esel,
                          const float* __restrict__ bias, float* __restrict__ out_sel,
                          unsigned* __restrict__ sel_pack, float* __restrict__ aff6) {
  int tok = blockIdx.x;
  int t = threadIdx.x;
  int e = t & 15, chunk = t >> 4;          // 16 experts x 16 chunks of 64 elems
  const float4* r4 = (const float4*)(selin + (size_t)tok * DMODEL + chunk * 64);
  const float4* w4 = (const float4*)(esel + (size_t)e * DMODEL + chunk * 64);
  float p = 0.f;
  #pragma unroll
  for (int i = 0; i < 16; i++) {
    float4 a = r4[i], b = w4[i];
    p += a.x * b.x + a.y * b.y + a.z * b.z + a.w * b.w;
  }
  __shared__ float part[16][17];
  __shared__ float aff[16];
  __shared__ float lbias[NROUTED];
  if (t < NROUTED) lbias[t] = bias[t];
  part[chunk][e] = p;
  __syncthreads();
  if (t < 16) {
    float s = 0.f;
    #pragma unroll
    for (int c = 0; c < 16; c++) s += part[c][t];
    aff[t] = 1.f / (1.f + expf(-s));
  }
  __syncthreads();
  if (t == 0) {
    unsigned pack = 0;
    unsigned taken = 0;
    #pragma unroll
    for (int k = 0; k < 4; k++) {
      float best = -3.4e38f; int bi = 0;
      for (int q = 0; q < NROUTED; q++) {
        if (taken & (1u << q)) continue;
        float v = aff[q] + lbias[q];
        if (v > best) { best = v; bi = q; }   // strict > => lowest index wins ties (top_k stable)
      }
      taken |= 1u << bi;
      pack |= (unsigned)bi << (4 * k);
      out_sel[(size_t)tok * KSEL + k] = (float)bi;
      aff6[(size_t)tok * KSEL + k] = aff[bi];
    }
    pack |= 14u << 16; pack |= 15u << 20;
    out_sel[(size_t)tok * KSEL + 4] = 14.f;
    out_sel[(size_t)tok * KSEL + 5] = 15.f;
    aff6[(size_t)tok * KSEL + 4] = aff[14];
    aff6[(size_t)tok * KSEL + 5] = aff[15];
    sel_pack[tok] = pack;
  }
}

// ---------------- routing pass B: hierarchical scatter into per-expert lists ----------
// counts padded: expert e lives at counts[e*16] (64B stride -> no cache-line sharing)
__global__ void scatter_k(const unsigned* __restrict__ sel_pack, const float* __restrict__ aff6,
                          int* __restrict__ counts, int* __restrict__ tokk,
                          float* __restrict__ affl) {
  __shared__ int lcnt[16], lbase[16], lcur[16];
  int t = threadIdx.x;
  int tok = blockIdx.x * 256 + t;
  if (t < 16) lcnt[t] = 0;
  __syncthreads();
  unsigned pack = sel_pack[tok];
  int eid[KSEL];
  #pragma unroll
  for (int k = 0; k < KSEL; k++) {
    eid[k] = (pack >> (4 * k)) & 15;
    atomicAdd(&lcnt[eid[k]], 1);
  }
  __syncthreads();
  if (t < 16) {
    lbase[t] = atomicAdd(&counts[t * 16], lcnt[t]);
    lcur[t] = 0;
  }
  __syncthreads();
  #pragma unroll
  for (int k = 0; k < KSEL; k++) {
    int e = eid[k];
    int slot = lbase[e] + atomicAdd(&lcur[e], 1);
    tokk[e * TOK_N + slot] = tok * 8 + k;
    affl[e * TOK_N + slot] = aff6[(size_t)tok * KSEL + k];
  }
}

// ---------------- build compact tile list (256-row tiles), expert-major, parallel -----
// tiles[slot] = e | (mtile << 8); all LDS-indexed (no scratch, rule #20).
__global__ void tilelist_k(const int* __restrict__ counts, int* __restrict__ tiles,
                           int* __restrict__ ntiles) {
  __shared__ int tc[16], pb[16];
  int t = threadIdx.x;   // 64 threads
  if (t < 16) tc[t] = (counts[t * 16] + 255) >> 8;
  __syncthreads();
  if (t == 0) {
    int s = 0;
    for (int e = 0; e < 16; e++) { pb[e] = s; s += tc[e]; }
    *ntiles = s;
  }
  __syncthreads();
  if (t < 16) {
    int b = pb[t], n = tc[t];
    for (int i = 0; i < n; i++) tiles[b + i] = t | (i << 8);
  }
}

// ---------------- grouped GEMM: 256x256x64 tile, 8 waves, T3+T4 pipelined ------------
// R12's counted-vmcnt schedule (STAGE(next) -> vmcnt(8) -> s_barrier -> COMPUTE(cur)
// -> s_barrier; never vmcnt(0) in main loop) with 4x the compute per phase: 8 waves
// (2Mx4N), each owning 128x64 (acc[8][4]), 64 MFMA/wave/phase (~400 issue cyc) so two
// phases cover the ~900-cyc gather latency that R12's 16-MFMA phases could not.
// LDS 2buf x (256x64 A + 256x64 B) x 2B = 128 KB -> 1 block/CU, 2 waves/SIMD.
// XOR swizzle: linear dest + pre-swizzled source chunk (j^(row&7)) + same XOR on read.
// Grid dim3(NY, MAXT): y innermost (per-XCD B-panel L2 residency, R9).
// PASS 2: A = Xbf by token; B = keysT [e][512][1024]; AK=1024; epi: aff*silu -> bf16
// PASS 3: A = scoresbf by pair; B = valuesT [e][1024][512]; AK=512; epi: atomicAdd f32
template<int AK, int PASS>
__global__ __launch_bounds__(512, 2) void moe_gemm_k(
    const u16* __restrict__ Abase, const u16* __restrict__ Bbase,
    const int* __restrict__ counts, const int* __restrict__ tokk,
    const float* __restrict__ affl, const int* __restrict__ tiles,
    const int* __restrict__ ntiles, u16* __restrict__ scores_out,
    float* __restrict__ out) {
  int slot = blockIdx.y;
  if (slot >= *ntiles) return;
  int desc = tiles[slot];
  int e = desc & 15;
  int m0 = (desc >> 8) << 8;
  int cnt = counts[e * 16];
  int n0 = blockIdx.x * 256;
  int t = threadIdx.x;
  int lane = t & 63, w = t >> 6;   // 8 waves
  int wr = w >> 2, wc = w & 3;     // 2x4 waves, each 128x64

  __shared__ u16 Al[2][256][64];   // double-buffered; linear (global_load_lds dest)
  __shared__ u16 Bl[2][256][64];   // 128 KB total

  const int* tl = tokk + e * TOK_N + m0;
  const float* al = affl + e * TOK_N + m0;
  const u16* Bp = Bbase + (size_t)e * 524288;

  f32x4 acc[8][4];
  #pragma unroll
  for (int m = 0; m < 8; m++)
    #pragma unroll
    for (int n = 0; n < 4; n++)
      acc[m][n] = (f32x4){0.f, 0.f, 0.f, 0.f};

  // staging: wave w stages rows [w*32, w*32+32) of A and B over 4 rounds of 8 rows.
  // lane -> row = base + (lane>>3), chunk j = lane&7; source chunk pre-swizzled j^(row&7).
  int jj = lane & 7, rl = lane >> 3;
  const u16* ag[4]; const u16* bg[4];
  #pragma unroll
  for (int r = 0; r < 4; r++) {
    int row = w * 32 + r * 8 + rl;
    int lr = (m0 + row < cnt) ? row : 0;   // clamp to a valid row (masked at epilogue)
    int tk = tl[lr];
    int ar = (PASS == 2) ? (tk >> 3) : ((tk >> 3) * 6 + (tk & 7));
    int cs = (jj ^ (row & 7)) * 8;         // swizzled source element offset
    ag[r] = Abase + (size_t)ar * AK + cs;
    bg[r] = Bp + (size_t)(n0 + row) * AK + cs;
  }

#define STAGE(B, K0)                                             \
  _Pragma("unroll")                                              \
  for (int r = 0; r < 4; r++) {                                  \
    gload_lds16(ag[r] + (K0), &Al[B][w * 32 + r * 8][0]);        \
    gload_lds16(bg[r] + (K0), &Bl[B][w * 32 + r * 8][0]);        \
  }

#define COMPUTE(B)                                                         \
  _Pragma("unroll")                                                        \
  for (int kk = 0; kk < 2; kk++) {                                         \
    int lc = kk * 4 + (lane >> 4);                                         \
    short8 af[8], bf[4];                                                   \
    _Pragma("unroll")                                                      \
    for (int m = 0; m < 8; m++) {                                          \
      int row = wr * 128 + m * 16 + (lane & 15);                           \
      af[m] = *(const short8*)&Al[B][row][(lc ^ (row & 7)) * 8];           \
    }                                                                      \
    _Pragma("unroll")                                                      \
    for (int n = 0; n < 4; n++) {                                          \
      int row = wc * 64 + n * 16 + (lane & 15);                            \
      bf[n] = *(const short8*)&Bl[B][row][(lc ^ (row & 7)) * 8];           \
    }                                                                      \
    _Pragma("unroll")                                                      \
    for (int m = 0; m < 8; m++)                                            \
      _Pragma("unroll")                                                    \
      for (int n = 0; n < 4; n++)                                          \
        acc[m][n] = __builtin_amdgcn_mfma_f32_16x16x32_bf16(af[m], bf[n],  \
                                                            acc[m][n], 0, 0, 0); \
  }

#define VWAIT8 asm volatile("s_waitcnt vmcnt(8)" ::: "memory")
#define VWAIT0 asm volatile("s_waitcnt vmcnt(0)" ::: "memory")
#define BARR  __builtin_amdgcn_s_barrier()
#define PIN   __builtin_amdgcn_sched_barrier(0)

  constexpr int NIT = AK / 64;   // 16 (pass2) / 8 (pass3) -- even, >= 4
  STAGE(0, 0)                    // 8 loads in flight (buf0)
  #pragma unroll 1
  for (int it = 0; it < NIT - 2; it += 2) {
    STAGE(1, (it + 1) * 64)      // +8 -> 16 in flight
    VWAIT8; BARR; PIN;           // buf0 done everywhere; buf1 loads still flying
    COMPUTE(0)
    BARR; PIN;                   // all waves done reading buf0 -> safe to overwrite
    STAGE(0, (it + 2) * 64)
    VWAIT8; BARR; PIN;           // buf1 done; buf0-next still flying
    COMPUTE(1)
    BARR; PIN;
  }
  // peeled tail: it = NIT-2
  STAGE(1, (NIT - 1) * 64)
  VWAIT8; BARR; PIN;
  COMPUTE(0)
  BARR; PIN;
  VWAIT0; BARR; PIN;             // drain buf1's loads
  COMPUTE(1)

#undef STAGE
#undef COMPUTE
#undef VWAIT8
#undef VWAIT0
#undef BARR
#undef PIN

  int cbase = n0 + wc * 64 + (lane & 15);
  #pragma unroll
  for (int m = 0; m < 8; m++) {
    int rbase = wr * 128 + m * 16 + ((lane >> 4) << 2);   // C/D: col=lane&15, row=(lane>>4)*4+q
    #pragma unroll
    for (int q = 0; q < 4; q++) {
      int row = rbase + q;
      if (m0 + row >= cnt) continue;
      int tk = tl[row];
      if (PASS == 2) {
        float aff = al[row];
        size_t base = (size_t)((tk >> 3) * 6 + (tk & 7)) * FEXP;
        #pragma unroll
        for (int n = 0; n < 4; n++) {
          float v = acc[m][n][q];
          float s = aff * v / (1.f + expf(-v));   // aff * silu(v)
          scores_out[base + cbase + n * 16] = f2bf(s);
        }
      } else {
        size_t base = (size_t)(tk >> 3) * DMODEL;
        #pragma unroll
        for (int n = 0; n < 4; n++)
          atomicAdd(&out[base + cbase + n * 16], acc[m][n][q]);
      }
    }
  }
}

extern "C" void kernel_launch(void* const* d_in, const int* in_sizes, int n_in,
                              void* d_out, int out_size, void* d_ws, size_t ws_size,
                              hipStream_t stream) {
  (void)in_sizes; (void)n_in; (void)out_size; (void)ws_size;
  const float* token_stream    = (const float*)d_in[0];
  const float* selection_input = (const float*)d_in[1];
  const float* keys_w          = (const float*)d_in[2];
  const float* values_w        = (const float*)d_in[3];
  const float* expert_sel      = (const float*)d_in[4];
  const float* bias_ffn        = (const float*)d_in[5];

  float* out     = (float*)d_out;                       // [8192][1024] f32
  float* out_sel = out + (size_t)TOK_N * DMODEL;        // [8192][6] as float

  char* ws = (char*)d_ws;
  u16*      Xbf      = (u16*)(ws + 0);                  // 16 MB
  u16*      keysT    = (u16*)(ws + 16777216);           // 16 MB  [e][512][1024]
  u16*      valuesT  = (u16*)(ws + 33554432);           // 16 MB  [e][1024][512]
  u16*      scoresbf = (u16*)(ws + 50331648);           // 48 MB  [49152][512]
  int*      counts   = (int*)(ws + 100663296);          // 1 KB (padded, e -> counts[e*16])
  int*      tokk     = (int*)(ws + 100664320);          // 512 KB
  float*    affl     = (float*)(ws + 101188608);        // 512 KB
  unsigned* sel_pack = (unsigned*)(ws + 101712896);     // 32 KB
  float*    aff6     = (float*)(ws + 101745664);        // 192 KB
  int*      tiles    = (int*)(ws + 101942272);          // 4 KB
  int*      ntiles   = (int*)(ws + 101946368);          // 4 B

  hipMemsetAsync(out, 0, (size_t)TOK_N * DMODEL * sizeof(float), stream);
  hipMemsetAsync(counts, 0, 1024, stream);

  cast_bf16_k<<<4096, 256, 0, stream>>>(token_stream, Xbf, TOK_N * DMODEL / 8);
  transpose_cast_k<<<dim3(16, 32, 16), dim3(32, 8), 0, stream>>>(keys_w, keysT, 1024, 512);
  transpose_cast_k<<<dim3(32, 16, 16), dim3(32, 8), 0, stream>>>(values_w, valuesT, 512, 1024);

  routing_k<<<TOK_N, 256, 0, stream>>>(selection_input, expert_sel, bias_ffn,
                                       out_sel, sel_pack, aff6);
  scatter_k<<<TOK_N / 256, 256, 0, stream>>>(sel_pack, aff6, counts, tokk, affl);
  tilelist_k<<<1, 64, 0, stream>>>(counts, tiles, ntiles);

  // scores = aff * silu(X @ K[e]):  M<=8192x6, N=512, K=1024
  moe_gemm_k<1024, 2><<<dim3(2, MAXT), 512, 0, stream>>>(Xbf, keysT, counts, tokk, affl,
                                                         tiles, ntiles, scoresbf, nullptr);
  // out += scores @ V[e]:          M<=8192x6, N=1024, K=512
  moe_gemm_k<512, 3><<<dim3(4, MAXT), 512, 0, stream>>>(scoresbf, valuesT, counts, tokk, affl,
                                                        tiles, ntiles, nullptr, out);
}

// Round 14
// 429.261 us; speedup vs baseline: 1.0291x; 1.0291x over previous
//
#include <hip/hip_runtime.h>

typedef short short8 __attribute__((ext_vector_type(8)));
typedef float f32x4 __attribute__((ext_vector_type(4)));
typedef unsigned short u16;

#define TOK_N 8192      // B*S
#define DMODEL 1024
#define NEXP 16
#define FEXP 512
#define NROUTED 14
#define KSEL 6
#define MAXTILES 400    // sum ceil(cnt_e/128) <= 49152/128 + 16

__device__ __forceinline__ u16 f2bf(float f) {
  unsigned u = __float_as_uint(f);
  u += 0x7fff + ((u >> 16) & 1);   // round-to-nearest-even
  return (u16)(u >> 16);
}

typedef const __attribute__((address_space(1))) unsigned int* gas_p;
typedef __attribute__((address_space(3))) unsigned int* las_p;
// wave-uniform LDS base + lane*16; per-lane global src (16B each)
__device__ __forceinline__ void gload_lds16(const void* g, void* l) {
  __builtin_amdgcn_global_load_lds((gas_p)g, (las_p)l, 16, 0, 0);
}

// ---------------- cast f32 -> bf16 (token stream) ----------------
__global__ void cast_bf16_k(const float* __restrict__ in, u16* __restrict__ out, int n8) {
  int i = blockIdx.x * blockDim.x + threadIdx.x;
  if (i >= n8) return;
  const float4* p = (const float4*)(in + (size_t)i * 8);
  float4 a = p[0], b = p[1];
  short8 v;
  v[0] = (short)f2bf(a.x); v[1] = (short)f2bf(a.y); v[2] = (short)f2bf(a.z); v[3] = (short)f2bf(a.w);
  v[4] = (short)f2bf(b.x); v[5] = (short)f2bf(b.y); v[6] = (short)f2bf(b.z); v[7] = (short)f2bf(b.w);
  *(short8*)(out + (size_t)i * 8) = v;
}

// ------------- transpose + cast: in [e][R][C] f32 -> out [e][C][R] bf16 -------------
__global__ void transpose_cast_k(const float* __restrict__ in, u16* __restrict__ out, int R, int C) {
  __shared__ u16 tile[32][33];
  int e = blockIdx.z;
  int c0 = blockIdx.x * 32, r0 = blockIdx.y * 32;
  int x = threadIdx.x, y = threadIdx.y;   // block (32,8)
  const float* ip = in + ((size_t)e * R + r0) * C + c0;
  #pragma unroll
  for (int i = 0; i < 4; i++)
    tile[y + 8 * i][x] = f2bf(ip[(size_t)(y + 8 * i) * C + x]);
  __syncthreads();
  u16* op = out + ((size_t)e * C + c0) * R + r0;
  #pragma unroll
  for (int i = 0; i < 4; i++)
    op[(size_t)(y + 8 * i) * R + x] = tile[x][y + 8 * i];
}

// ---------------- routing pass A: logits, sigmoid, stable top-4 (NO global atomics) ----
__global__ void routing_k(const float* __restrict__ selin, const float* __restrict__ esel,
                          const float* __restrict__ bias, float* __restrict__ out_sel,
                          unsigned* __restrict__ sel_pack, float* __restrict__ aff6) {
  int tok = blockIdx.x;
  int t = threadIdx.x;
  int e = t & 15, chunk = t >> 4;          // 16 experts x 16 chunks of 64 elems
  const float4* r4 = (const float4*)(selin + (size_t)tok * DMODEL + chunk * 64);
  const float4* w4 = (const float4*)(esel + (size_t)e * DMODEL + chunk * 64);
  float p = 0.f;
  #pragma unroll
  for (int i = 0; i < 16; i++) {
    float4 a = r4[i], b = w4[i];
    p += a.x * b.x + a.y * b.y + a.z * b.z + a.w * b.w;
  }
  __shared__ float part[16][17];
  __shared__ float aff[16];
  __shared__ float lbias[NROUTED];
  if (t < NROUTED) lbias[t] = bias[t];
  part[chunk][e] = p;
  __syncthreads();
  if (t < 16) {
    float s = 0.f;
    #pragma unroll
    for (int c = 0; c < 16; c++) s += part[c][t];
    aff[t] = 1.f / (1.f + expf(-s));
  }
  __syncthreads();
  if (t == 0) {
    unsigned pack = 0;
    unsigned taken = 0;
    #pragma unroll
    for (int k = 0; k < 4; k++) {
      float best = -3.4e38f; int bi = 0;
      for (int q = 0; q < NROUTED; q++) {
        if (taken & (1u << q)) continue;
        float v = aff[q] + lbias[q];
        if (v > best) { best = v; bi = q; }   // strict > => lowest index wins ties (top_k stable)
      }
      taken |= 1u << bi;
      pack |= (unsigned)bi << (4 * k);
      out_sel[(size_t)tok * KSEL + k] = (float)bi;
      aff6[(size_t)tok * KSEL + k] = aff[bi];
    }
    pack |= 14u << 16; pack |= 15u << 20;
    out_sel[(size_t)tok * KSEL + 4] = 14.f;
    out_sel[(size_t)tok * KSEL + 5] = 15.f;
    aff6[(size_t)tok * KSEL + 4] = aff[14];
    aff6[(size_t)tok * KSEL + 5] = aff[15];
    sel_pack[tok] = pack;
  }
}

// ---------------- routing pass B: hierarchical scatter into per-expert lists ----------
// counts padded: expert e lives at counts[e*16] (64B stride -> no cache-line sharing)
__global__ void scatter_k(const unsigned* __restrict__ sel_pack, const float* __restrict__ aff6,
                          int* __restrict__ counts, int* __restrict__ tokk,
                          float* __restrict__ affl) {
  __shared__ int lcnt[16], lbase[16], lcur[16];
  int t = threadIdx.x;
  int tok = blockIdx.x * 256 + t;
  if (t < 16) lcnt[t] = 0;
  __syncthreads();
  unsigned pack = sel_pack[tok];
  int eid[KSEL];
  #pragma unroll
  for (int k = 0; k < KSEL; k++) {
    eid[k] = (pack >> (4 * k)) & 15;
    atomicAdd(&lcnt[eid[k]], 1);
  }
  __syncthreads();
  if (t < 16) {
    lbase[t] = atomicAdd(&counts[t * 16], lcnt[t]);
    lcur[t] = 0;
  }
  __syncthreads();
  #pragma unroll
  for (int k = 0; k < KSEL; k++) {
    int e = eid[k];
    int slot = lbase[e] + atomicAdd(&lcur[e], 1);
    tokk[e * TOK_N + slot] = tok * 8 + k;
    affl[e * TOK_N + slot] = aff6[(size_t)tok * KSEL + k];
  }
}

// ---------------- build compact tile list + per-expert prefix base, parallel ----------
// tiles[slot] = e | (mtile << 8); pbase[e] = exclusive prefix of raw counts (scores
// rows are packed per-expert in list order). All LDS-indexed (no scratch, rule #20).
__global__ void tilelist_k(const int* __restrict__ counts, int* __restrict__ tiles,
                           int* __restrict__ ntiles, int* __restrict__ pbase) {
  __shared__ int tc[16], pb[16];
  int t = threadIdx.x;   // 64 threads
  if (t < 16) tc[t] = (counts[t * 16] + 127) >> 7;
  __syncthreads();
  if (t == 0) {
    int s = 0;
    for (int e = 0; e < 16; e++) { pb[e] = s; s += tc[e]; }
    *ntiles = s;
    int s2 = 0;
    for (int e = 0; e < 16; e++) { pbase[e] = s2; s2 += counts[e * 16]; }
  }
  __syncthreads();
  if (t < 16) {
    int b = pb[t], n = tc[t];
    for (int i = 0; i < n; i++) tiles[b + i] = t | (i << 8);
  }
}

// ---------------- grouped GEMM: T3+T4 pipelined, LIST-ORDER scores layout -----------
// R12 core: STAGE(next buf) -> s_waitcnt vmcnt(8) (next-buf loads stay IN FLIGHT) ->
// s_barrier -> COMPUTE(cur) -> s_barrier; never vmcnt(0) in main loop. LDS 2x32KB.
// NEW (R14): scores stored at row pbase[e]+list_slot (not token order):
//   pass-2 epilogue writes CONTIGUOUS rows (kills the 4x partial-line WRITE
//   amplification, 196->~55MB) and pass-3's A needs NO gather at all (contiguous).
// PASS 2: A = Xbf gathered by token; B = keysT [e][512][1024]; AK=1024
// PASS 3: A = scores (list-order, contiguous); B = valuesT [e][1024][512]; AK=512
//         epilogue: atomicAdd f32 into out[tok][1024] (scatter via tokk)
template<int AK, int PASS>
__global__ __launch_bounds__(256, 2) void moe_gemm_k(
    const u16* __restrict__ Abase, const u16* __restrict__ Bbase,
    const int* __restrict__ counts, const int* __restrict__ tokk,
    const float* __restrict__ affl, const int* __restrict__ tiles,
    const int* __restrict__ ntiles, const int* __restrict__ pbase,
    u16* __restrict__ scores_out, float* __restrict__ out) {
  int slot = blockIdx.y;
  if (slot >= *ntiles) return;
  int desc = tiles[slot];
  int e = desc & 15;
  int m0 = (desc >> 8) << 7;
  int cnt = counts[e * 16];
  int pbe = pbase[e];
  int n0 = blockIdx.x * 128;
  int t = threadIdx.x;
  int lane = t & 63, w = t >> 6;
  int wr = w >> 1, wc = w & 1;   // 2x2 waves, each 64x64

  __shared__ u16 Al[2][128][64];   // double-buffered; linear (global_load_lds dest)
  __shared__ u16 Bl[2][128][64];

  const int* tl = tokk + e * TOK_N + m0;
  const float* al = affl + e * TOK_N + m0;
  const u16* Bp = Bbase + (size_t)e * 524288;

  f32x4 acc[4][4];
  #pragma unroll
  for (int m = 0; m < 4; m++)
    #pragma unroll
    for (int n = 0; n < 4; n++)
      acc[m][n] = (f32x4){0.f, 0.f, 0.f, 0.f};

  // staging geometry: per r (r<4), wave w stages rows [r*32+w*8, +8): 64 lanes x 16B = 1KB.
  // lane -> row = base + (lane>>3), chunk j = lane&7; source chunk pre-swizzled j^(row&7).
  int jj = lane & 7, rl = lane >> 3;
  const u16* ag[4]; const u16* bg[4];
  #pragma unroll
  for (int r = 0; r < 4; r++) {
    int row = r * 32 + w * 8 + rl;
    int lr = (m0 + row < cnt) ? row : 0;   // clamp to a valid row (masked at epilogue)
    int ar;
    if (PASS == 2) {
      int tk = tl[lr];
      ar = tk >> 3;                        // gather X row by token
    } else {
      ar = pbe + m0 + lr;                  // contiguous list-order scores row
    }
    int cs = (jj ^ (row & 7)) * 8;         // swizzled source element offset
    ag[r] = Abase + (size_t)ar * AK + cs;
    bg[r] = Bp + (size_t)(n0 + row) * AK + cs;
  }

#define STAGE(B, K0)                                             \
  _Pragma("unroll")                                              \
  for (int r = 0; r < 4; r++) {                                  \
    gload_lds16(ag[r] + (K0), &Al[B][r * 32 + w * 8][0]);        \
    gload_lds16(bg[r] + (K0), &Bl[B][r * 32 + w * 8][0]);        \
  }

#define COMPUTE(B)                                                         \
  _Pragma("unroll")                                                        \
  for (int kk = 0; kk < 2; kk++) {                                         \
    int lc = kk * 4 + (lane >> 4);                                         \
    short8 af[4], bf[4];                                                   \
    _Pragma("unroll")                                                      \
    for (int m = 0; m < 4; m++) {                                          \
      int row = wr * 64 + m * 16 + (lane & 15);                            \
      af[m] = *(const short8*)&Al[B][row][(lc ^ (row & 7)) * 8];           \
    }                                                                      \
    _Pragma("unroll")                                                      \
    for (int n = 0; n < 4; n++) {                                          \
      int row = wc * 64 + n * 16 + (lane & 15);                            \
      bf[n] = *(const short8*)&Bl[B][row][(lc ^ (row & 7)) * 8];           \
    }                                                                      \
    _Pragma("unroll")                                                      \
    for (int m = 0; m < 4; m++)                                            \
      _Pragma("unroll")                                                    \
      for (int n = 0; n < 4; n++)                                          \
        acc[m][n] = __builtin_amdgcn_mfma_f32_16x16x32_bf16(af[m], bf[n],  \
                                                            acc[m][n], 0, 0, 0); \
  }

#define VWAIT8 asm volatile("s_waitcnt vmcnt(8)" ::: "memory")
#define VWAIT0 asm volatile("s_waitcnt vmcnt(0)" ::: "memory")
#define BARR  __builtin_amdgcn_s_barrier()
#define PIN   __builtin_amdgcn_sched_barrier(0)

  constexpr int NIT = AK / 64;   // 16 (pass2) / 8 (pass3) -- even, >= 4
  STAGE(0, 0)                    // 8 loads in flight (buf0)
  #pragma unroll 1
  for (int it = 0; it < NIT - 2; it += 2) {
    STAGE(1, (it + 1) * 64)      // +8 -> 16 in flight
    VWAIT8; BARR; PIN;           // buf0 done everywhere; buf1 loads still flying
    COMPUTE(0)
    BARR; PIN;                   // all waves done reading buf0 -> safe to overwrite
    STAGE(0, (it + 2) * 64)
    VWAIT8; BARR; PIN;           // buf1 done; buf0-next still flying
    COMPUTE(1)
    BARR; PIN;
  }
  // peeled tail: it = NIT-2
  STAGE(1, (NIT - 1) * 64)
  VWAIT8; BARR; PIN;
  COMPUTE(0)
  BARR; PIN;
  VWAIT0; BARR; PIN;             // drain buf1's loads
  COMPUTE(1)

#undef STAGE
#undef COMPUTE
#undef VWAIT8
#undef VWAIT0
#undef BARR
#undef PIN

  int cbase = n0 + wc * 64 + (lane & 15);
  #pragma unroll
  for (int m = 0; m < 4; m++) {
    int rbase = wr * 64 + m * 16 + ((lane >> 4) << 2);   // C/D: col=lane&15, row=(lane>>4)*4+q
    #pragma unroll
    for (int q = 0; q < 4; q++) {
      int row = rbase + q;
      if (m0 + row >= cnt) continue;
      if (PASS == 2) {
        float aff = al[row];
        size_t base = (size_t)(pbe + m0 + row) * FEXP;   // contiguous list-order row
        #pragma unroll
        for (int n = 0; n < 4; n++) {
          float v = acc[m][n][q];
          float s = aff * v / (1.f + expf(-v));   // aff * silu(v)
          scores_out[base + cbase + n * 16] = f2bf(s);
        }
      } else {
        int tk = tl[row];
        size_t base = (size_t)(tk >> 3) * DMODEL;
        #pragma unroll
        for (int n = 0; n < 4; n++)
          atomicAdd(&out[base + cbase + n * 16], acc[m][n][q]);
      }
    }
  }
}

extern "C" void kernel_launch(void* const* d_in, const int* in_sizes, int n_in,
                              void* d_out, int out_size, void* d_ws, size_t ws_size,
                              hipStream_t stream) {
  (void)in_sizes; (void)n_in; (void)out_size; (void)ws_size;
  const float* token_stream    = (const float*)d_in[0];
  const float* selection_input = (const float*)d_in[1];
  const float* keys_w          = (const float*)d_in[2];
  const float* values_w        = (const float*)d_in[3];
  const float* expert_sel      = (const float*)d_in[4];
  const float* bias_ffn        = (const float*)d_in[5];

  float* out     = (float*)d_out;                       // [8192][1024] f32
  float* out_sel = out + (size_t)TOK_N * DMODEL;        // [8192][6] as float

  char* ws = (char*)d_ws;
  u16*      Xbf      = (u16*)(ws + 0);                  // 16 MB
  u16*      keysT    = (u16*)(ws + 16777216);           // 16 MB  [e][512][1024]
  u16*      valuesT  = (u16*)(ws + 33554432);           // 16 MB  [e][1024][512]
  u16*      scoresbf = (u16*)(ws + 50331648);           // 48 MB  [49152 list-order][512]
  int*      counts   = (int*)(ws + 100663296);          // 1 KB (padded, e -> counts[e*16])
  int*      tokk     = (int*)(ws + 100664320);          // 512 KB
  float*    affl     = (float*)(ws + 101188608);        // 512 KB
  unsigned* sel_pack = (unsigned*)(ws + 101712896);     // 32 KB
  float*    aff6     = (float*)(ws + 101745664);        // 192 KB
  int*      tiles    = (int*)(ws + 101942272);          // 4 KB
  int*      ntiles   = (int*)(ws + 101946368);          // 4 B
  int*      pbase    = (int*)(ws + 101946432);          // 64 B

  hipMemsetAsync(out, 0, (size_t)TOK_N * DMODEL * sizeof(float), stream);
  hipMemsetAsync(counts, 0, 1024, stream);

  cast_bf16_k<<<4096, 256, 0, stream>>>(token_stream, Xbf, TOK_N * DMODEL / 8);
  transpose_cast_k<<<dim3(16, 32, 16), dim3(32, 8), 0, stream>>>(keys_w, keysT, 1024, 512);
  transpose_cast_k<<<dim3(32, 16, 16), dim3(32, 8), 0, stream>>>(values_w, valuesT, 512, 1024);

  routing_k<<<TOK_N, 256, 0, stream>>>(selection_input, expert_sel, bias_ffn,
                                       out_sel, sel_pack, aff6);
  scatter_k<<<TOK_N / 256, 256, 0, stream>>>(sel_pack, aff6, counts, tokk, affl);
  tilelist_k<<<1, 64, 0, stream>>>(counts, tiles, ntiles, pbase);

  // scores = aff * silu(X @ K[e]):  M<=49152, N=512, K=1024
  moe_gemm_k<1024, 2><<<dim3(4, MAXTILES), 256, 0, stream>>>(Xbf, keysT, counts, tokk, affl,
                                                             tiles, ntiles, pbase,
                                                             scoresbf, nullptr);
  // out += scores @ V[e]:          M<=49152, N=1024, K=512
  moe_gemm_k<512, 3><<<dim3(8, MAXTILES), 256, 0, stream>>>(scoresbf, valuesT, counts, tokk, affl,
                                                            tiles, ntiles, pbase,
                                                            nullptr, out);
}